// Round 2
// baseline (2178.499 us; speedup 1.0000x reference)
//
#include <hip/hip_runtime.h>
#include <cstdint>
#include <cstddef>

#define N 8192
#define D 128
#define KNN 20
#define NC 10
#define CAP 2048
constexpr float EPS = 1e-10f;

// ---------------- K1: squared norms ----------------
__global__ void k_sqnorm(const float* __restrict__ X, float* __restrict__ sq) {
    int row = blockIdx.x;
    int lane = threadIdx.x;
    const float2* X2 = (const float2*)(X + (size_t)row * D);
    float2 a = X2[lane];
    float s = a.x * a.x + a.y * a.y;
    #pragma unroll
    for (int off = 32; off; off >>= 1) s += __shfl_down(s, off, 64);
    if (lane == 0) sq[row] = s;
}

// ---------------- K2: column sums  xbsum[d]=sum_j X[j][d], wvsum[d]=sum_j X[j][d]*sq[j] ----
__global__ void k_colstats(const float* __restrict__ X, const float* __restrict__ sq,
                           float* __restrict__ xbsum, float* __restrict__ wvsum) {
    __shared__ float redx[256], redw[256];
    int t = threadIdx.x;
    int c = t & 127, h = t >> 7;
    int j0 = blockIdx.x * 128;
    float sx = 0.f, sw = 0.f;
    for (int it = 0; it < 64; ++it) {
        int j = j0 + h + 2 * it;
        float x = X[(size_t)j * D + c];
        sx += x;
        sw = fmaf(x, sq[j], sw);
    }
    redx[t] = sx; redw[t] = sw; __syncthreads();
    if (t < 128) {
        atomicAdd(&xbsum[t], redx[t] + redx[t + 128]);
        atomicAdd(&wvsum[t], redw[t] + redw[t + 128]);
    }
}

// ---------------- K3: scalar stats of sq:  scal[0]=mean(sq), scal[1]=var(sq) ----
__global__ void k_sqred(const float* __restrict__ sq, float* __restrict__ scal) {
    __shared__ float r1[256], r2[256];
    int t = threadIdx.x;
    float s1 = 0.f, s2 = 0.f;
    for (int i = t; i < N; i += 256) { float x = sq[i]; s1 += x; s2 = fmaf(x, x, s2); }
    r1[t] = s1; r2[t] = s2; __syncthreads();
    for (int s = 128; s; s >>= 1) {
        if (t < s) { r1[t] += r1[t + s]; r2[t] += r2[t + s]; }
        __syncthreads();
    }
    if (t == 0) { float m = r1[0] / N; scal[0] = m; scal[1] = r2[0] / N - m * m; }
}

// ---------------- K4: partial M = X^T X  (128 blocks x 64 rows each) ----------------
__global__ __launch_bounds__(256) void k_Mpart(const float* __restrict__ X,
                                               float* __restrict__ Mpart) {
    __shared__ float Xs[64 * 132];
    int t = threadIdx.x;
    int j0 = blockIdx.x * 64;
    const float4* X4 = (const float4*)X;
    #pragma unroll
    for (int p = 0; p < 8; ++p) {
        int u = t + 256 * p, r = u >> 5, kq = u & 31;
        *(float4*)&Xs[r * 132 + kq * 4] = X4[(size_t)(j0 + r) * 32 + kq];
    }
    __syncthreads();
    int a0 = (t & 15) * 8, b0 = (t >> 4) * 8;
    float acc[8][8] = {};
    for (int j = 0; j < 64; ++j) {
        float av[8], bv[8];
        *(float4*)&av[0] = *(const float4*)&Xs[j * 132 + a0];
        *(float4*)&av[4] = *(const float4*)&Xs[j * 132 + a0 + 4];
        *(float4*)&bv[0] = *(const float4*)&Xs[j * 132 + b0];
        *(float4*)&bv[4] = *(const float4*)&Xs[j * 132 + b0 + 4];
        #pragma unroll
        for (int i = 0; i < 8; ++i)
            #pragma unroll
            for (int k = 0; k < 8; ++k) acc[i][k] = fmaf(av[i], bv[k], acc[i][k]);
    }
    float* outp = Mpart + (size_t)blockIdx.x * 16384;
    #pragma unroll
    for (int i = 0; i < 8; ++i) {
        *(float4*)&outp[(a0 + i) * 128 + b0]     = *(float4*)&acc[i][0];
        *(float4*)&outp[(a0 + i) * 128 + b0 + 4] = *(float4*)&acc[i][4];
    }
}

__global__ void k_Mred(const float* __restrict__ Mpart, float* __restrict__ M) {
    int e = blockIdx.x * 256 + threadIdx.x;    // grid 64 -> 16384
    float s = 0.f;
    for (int b = 0; b < 128; ++b) s += Mpart[(size_t)b * 16384 + e];
    M[e] = s;
}

// ---------------- K5: Y = X * M  (raw; q_i = x_i . y_i) ----------------
__global__ __launch_bounds__(256) void k_gemmY(const float* __restrict__ X,
                                               const float* __restrict__ Mm,
                                               float* __restrict__ Y) {
    __shared__ float As[64 * 68];
    __shared__ float Bs[64 * 68];
    int t = threadIdx.x, tx = t & 15, ty = t >> 4;
    int rowTile = blockIdx.y * 64, colTile = blockIdx.x * 64;
    const float4* X4 = (const float4*)X;
    const float4* M4 = (const float4*)Mm;
    float acc[4][4] = {};
    #pragma unroll
    for (int s = 0; s < 2; ++s) {
        __syncthreads();
        #pragma unroll
        for (int p = 0; p < 4; ++p) {
            int u = t + 256 * p, r = u >> 4, k4 = u & 15;
            *(float4*)&As[r * 68 + k4 * 4] = X4[(size_t)(rowTile + r) * 32 + s * 16 + k4];
            *(float4*)&Bs[r * 68 + k4 * 4] = M4[(size_t)(colTile + r) * 32 + s * 16 + k4];
        }
        __syncthreads();
        #pragma unroll
        for (int k4 = 0; k4 < 16; ++k4) {
            float4 a4[4], b4[4];
            #pragma unroll
            for (int q = 0; q < 4; ++q) a4[q] = *(const float4*)&As[(ty + 16 * q) * 68 + k4 * 4];
            #pragma unroll
            for (int q = 0; q < 4; ++q) b4[q] = *(const float4*)&Bs[(tx + 16 * q) * 68 + k4 * 4];
            #pragma unroll
            for (int i = 0; i < 4; ++i)
                #pragma unroll
                for (int j = 0; j < 4; ++j) {
                    acc[i][j] = fmaf(a4[i].x, b4[j].x, acc[i][j]);
                    acc[i][j] = fmaf(a4[i].y, b4[j].y, acc[i][j]);
                    acc[i][j] = fmaf(a4[i].z, b4[j].z, acc[i][j]);
                    acc[i][j] = fmaf(a4[i].w, b4[j].w, acc[i][j]);
                }
        }
    }
    #pragma unroll
    for (int i = 0; i < 4; ++i)
        #pragma unroll
        for (int j = 0; j < 4; ++j)
            Y[(size_t)(rowTile + ty + 16 * i) * 128 + colTile + tx + 16 * j] = acc[i][j];
}

// ---------------- K6: per-row threshold T = mu - 2.2*sigma (closed form) ----------
__global__ __launch_bounds__(256) void k_thresh(const float* __restrict__ X,
        const float* __restrict__ Y, const float* __restrict__ sqn,
        const float* __restrict__ xbsum, const float* __restrict__ wvsum,
        const float* __restrict__ scal, float* __restrict__ T) {
    int t = threadIdx.x;
    int row = blockIdx.x * 4 + (t >> 6);
    int lane = t & 63;
    const float2* X2 = (const float2*)X;
    const float2* Y2 = (const float2*)Y;
    const float2* B2 = (const float2*)xbsum;
    const float2* W2 = (const float2*)wvsum;
    float2 x = X2[(size_t)row * 64 + lane];
    float2 y = Y2[(size_t)row * 64 + lane];
    float2 b = B2[lane];
    float2 w = W2[lane];
    float pa = x.x * b.x + x.y * b.y;
    float pc = x.x * w.x + x.y * w.y;
    float pq = x.x * y.x + x.y * y.y;
    #pragma unroll
    for (int off = 32; off; off >>= 1) {
        pa += __shfl_down(pa, off, 64);
        pc += __shfl_down(pc, off, 64);
        pq += __shfl_down(pq, off, 64);
    }
    if (lane == 0) {
        const float inv = 1.f / N;
        float a = pa * inv, c = pc * inv, q = pq * inv;
        float m_sq = scal[0], vs = scal[1];
        float mu  = sqn[row] + m_sq - 2.f * a;
        float var = vs + 4.f * (q - a * a) - 4.f * (c - m_sq * a);
        T[row] = mu - 2.2f * sqrtf(fmaxf(var, 0.f));
    }
}

// ---------------- K7: fused upper-triangle distance GEMM + threshold scatter ----
// One 64x64 tile per block; 8256 blocks. No d2 matrix in HBM.
__global__ __launch_bounds__(256) void k_fused(const float* __restrict__ X,
        const float* __restrict__ sqn, const float* __restrict__ T,
        unsigned long long* __restrict__ list, int* __restrict__ cnt8) {
    __shared__ float As[64 * 68];
    __shared__ float Bs[64 * 68];
    int L = blockIdx.x;
    float ff = (257.0f - sqrtf(66049.0f - 8.0f * (float)L)) * 0.5f;
    int rt = (int)ff;
    if (rt > 127) rt = 127;
    while (rt > 0 && (rt * 128 - rt * (rt - 1) / 2) > L) --rt;
    while (((rt + 1) * 128 - (rt + 1) * rt / 2) <= L) ++rt;
    int ct = rt + (L - (rt * 128 - rt * (rt - 1) / 2));
    int rowTile = rt << 6, colTile = ct << 6;
    bool diag = (rt == ct);

    int t = threadIdx.x, tx = t & 15, ty = t >> 4;
    const float4* X4 = (const float4*)X;

    float sqa[4], Ta_[4], sqb[4], Tb_[4];
    int gr[4], gc[4];
    #pragma unroll
    for (int q = 0; q < 4; ++q) {
        gr[q] = rowTile + ty + 16 * q;
        gc[q] = colTile + tx + 16 * q;
        sqa[q] = sqn[gr[q]]; Ta_[q] = T[gr[q]];
        sqb[q] = sqn[gc[q]]; Tb_[q] = T[gc[q]];
    }

    float acc[4][4] = {};
    #pragma unroll
    for (int s = 0; s < 2; ++s) {
        __syncthreads();
        #pragma unroll
        for (int p = 0; p < 4; ++p) {
            int u = t + 256 * p, r = u >> 4, k4 = u & 15;
            *(float4*)&As[r * 68 + k4 * 4] = X4[(size_t)(rowTile + r) * 32 + s * 16 + k4];
            *(float4*)&Bs[r * 68 + k4 * 4] = X4[(size_t)(colTile + r) * 32 + s * 16 + k4];
        }
        __syncthreads();
        #pragma unroll
        for (int k4 = 0; k4 < 16; ++k4) {
            float4 a4[4], b4[4];
            #pragma unroll
            for (int q = 0; q < 4; ++q) a4[q] = *(const float4*)&As[(ty + 16 * q) * 68 + k4 * 4];
            #pragma unroll
            for (int q = 0; q < 4; ++q) b4[q] = *(const float4*)&Bs[(tx + 16 * q) * 68 + k4 * 4];
            #pragma unroll
            for (int i = 0; i < 4; ++i)
                #pragma unroll
                for (int j = 0; j < 4; ++j) {
                    acc[i][j] = fmaf(a4[i].x, b4[j].x, acc[i][j]);
                    acc[i][j] = fmaf(a4[i].y, b4[j].y, acc[i][j]);
                    acc[i][j] = fmaf(a4[i].z, b4[j].z, acc[i][j]);
                    acc[i][j] = fmaf(a4[i].w, b4[j].w, acc[i][j]);
                }
        }
    }
    #pragma unroll
    for (int i = 0; i < 4; ++i)
        #pragma unroll
        for (int j = 0; j < 4; ++j) {
            float d2 = fmaxf(sqa[i] + sqb[j] - 2.f * acc[i][j], 0.f);
            unsigned ub = __float_as_uint(d2);
            if (d2 < Ta_[i]) {                       // row-side push
                int pos = atomicAdd(&cnt8[gr[i]], 1);
                if (pos < CAP)
                    list[(size_t)gr[i] * CAP + pos] =
                        ((unsigned long long)ub << 14) | (unsigned long long)(gc[j] + 1);
            }
            if (!diag && d2 < Tb_[j]) {              // mirrored col-side push
                int pos = atomicAdd(&cnt8[gc[j]], 1);
                if (pos < CAP)
                    list[(size_t)gc[j] * CAP + pos] =
                        ((unsigned long long)ub << 14) | (unsigned long long)(gr[i] + 1);
            }
        }
}

// ---------------- K8: exact top-20 from candidate list (one wave per row) ----------
__global__ void k_top(const unsigned long long* __restrict__ list,
                      const int* __restrict__ cnt8, int* __restrict__ knn_idx,
                      float* __restrict__ density, int* __restrict__ flagv) {
    int row = blockIdx.x, t = threadIdx.x;
    int cnt = cnt8[row];
    bool bad = (cnt < KNN) || (cnt > CAP);
    if (t == 0) flagv[row] = bad ? 1 : 0;
    if (bad) return;
    const unsigned long long* Lp = list + (size_t)row * CAP;
    unsigned long long last = 0ull;
    float sumd = 0.f;
    for (int r = 0; r < KNN; ++r) {
        unsigned long long m = ~0ull;
        for (int s = t; s < cnt; s += 64) {
            unsigned long long k = Lp[s];
            if (k > last && k < m) m = k;
        }
        #pragma unroll
        for (int off = 32; off; off >>= 1) {
            unsigned long long o = __shfl_down(m, off, 64);
            if (o < m) m = o;
        }
        m = __shfl(m, 0, 64);
        last = m;
        if (t == 0) {
            int j = (int)(m & 16383ull) - 1;
            if (j < 0) j = 0; if (j >= N) j = N - 1;
            knn_idx[(size_t)row * KNN + r] = j;
            sumd += sqrtf(__uint_as_float((unsigned)(m >> 14)));
        }
    }
    if (t == 0) density[row] = 1.f / (sumd * (1.f / KNN) + EPS);
}

// ---------------- K9: exact fallback for flagged rows (expected: none) ----------
__global__ __launch_bounds__(256) void k_fb(const float* __restrict__ X,
        const float* __restrict__ sqn, const int* __restrict__ flagv,
        int* __restrict__ knn_idx, float* __restrict__ density) {
    int row = blockIdx.x;
    if (flagv[row] == 0) return;
    __shared__ float xi[128];
    __shared__ float drow[N];
    __shared__ float redf1[256], redf2[256];
    __shared__ int redi[256];
    __shared__ unsigned long long lst[CAP];
    __shared__ int lc;
    int t = threadIdx.x;
    if (t < 32) *(float4*)&xi[t * 4] = ((const float4*)X)[(size_t)row * 32 + t];
    __syncthreads();
    float sqi = sqn[row];
    for (int p = 0; p < 32; ++p) {
        int j = t + 256 * p;
        const float4* xj = (const float4*)X + (size_t)j * 32;
        float dot = 0.f;
        #pragma unroll
        for (int d4 = 0; d4 < 32; ++d4) {
            float4 a = xj[d4];
            float4 b = *(const float4*)&xi[d4 * 4];
            dot = fmaf(a.x, b.x, dot); dot = fmaf(a.y, b.y, dot);
            dot = fmaf(a.z, b.z, dot); dot = fmaf(a.w, b.w, dot);
        }
        drow[j] = fmaxf(sqi + sqn[j] - 2.f * dot, 0.f);
    }
    __syncthreads();
    float s1 = 0.f, s2 = 0.f;
    for (int p = 0; p < 32; ++p) { float x = drow[t + 256 * p]; s1 += x; s2 = fmaf(x, x, s2); }
    redf1[t] = s1; redf2[t] = s2; __syncthreads();
    for (int s = 128; s; s >>= 1) {
        if (t < s) { redf1[t] += redf1[t + s]; redf2[t] += redf2[t + s]; }
        __syncthreads();
    }
    float mu = redf1[0] * (1.f / N);
    float var = redf2[0] * (1.f / N) - mu * mu;
    float sigma = sqrtf(fmaxf(var, 0.f)) + 1e-6f;
    __syncthreads();
    float Tlo = 0.f, Thi = mu, T = mu - 2.2f * sigma;
    if (T <= 0.f) T = 0.5f * (Tlo + Thi);
    for (int it = 0; it < 32; ++it) {
        int c = 0;
        for (int p = 0; p < 32; ++p) c += (drow[t + 256 * p] < T) ? 1 : 0;
        redi[t] = c; __syncthreads();
        for (int s = 128; s; s >>= 1) {
            if (t < s) redi[t] += redi[t + s];
            __syncthreads();
        }
        int n = redi[0]; __syncthreads();
        if (n >= KNN && n <= CAP) break;
        if (n < KNN) Tlo = T; else Thi = T;
        T = 0.5f * (Tlo + Thi);
    }
    if (t == 0) lc = 0;
    __syncthreads();
    for (int p = 0; p < 32; ++p) {
        int j = t + 256 * p;
        float x = drow[j];
        if (x < T) {
            int pos = atomicAdd(&lc, 1);
            if (pos < CAP)
                lst[pos] = ((unsigned long long)__float_as_uint(x) << 14) |
                           (unsigned long long)(j + 1);
        }
    }
    __syncthreads();
    int n = min(lc, CAP);
    if (t < 64) {
        unsigned long long last = 0ull; float sumd = 0.f;
        for (int r = 0; r < KNN; ++r) {
            unsigned long long m = ~0ull;
            for (int s = t; s < n; s += 64) {
                unsigned long long k = lst[s];
                if (k > last && k < m) m = k;
            }
            #pragma unroll
            for (int off = 32; off; off >>= 1) {
                unsigned long long o = __shfl_down(m, off, 64);
                if (o < m) m = o;
            }
            m = __shfl(m, 0, 64);
            last = m;
            if (t == 0) {
                int j = (int)(m & 16383ull) - 1;
                if (j < 0) j = 0; if (j >= N) j = N - 1;
                knn_idx[(size_t)row * KNN + r] = j;
                sumd += sqrtf(__uint_as_float((unsigned)(m >> 14)));
            }
        }
        if (t == 0) density[row] = 1.f / (sumd * (1.f / KNN) + EPS);
    }
}

// ---------------- K10: scatter knn + rnn (deduped) contributions ----------------
__global__ void k_scatter(const int* __restrict__ knn_idx, const float* __restrict__ density,
                          float* __restrict__ numer, float* __restrict__ cnt) {
    int p = blockIdx.x * 256 + threadIdx.x;
    if (p >= N * KNN) return;
    int i = p / KNN;
    int j = knn_idx[p];
    atomicAdd(&numer[i], density[j]);
    atomicAdd(&cnt[i], 1.f);
    bool found = false;
    const int* kj = knn_idx + (size_t)j * KNN;
    #pragma unroll
    for (int m = 0; m < KNN; ++m) found |= (kj[m] == i);
    if (!found) {
        atomicAdd(&numer[j], density[i]);
        atomicAdd(&cnt[j], 1.f);
    }
}

// ---------------- K11: scores, flags, class preds ----------------
__global__ void k_final(const float* __restrict__ density, const float* __restrict__ numer,
                        const float* __restrict__ cnt, const float* __restrict__ logits,
                        float* __restrict__ out) {
    int i = blockIdx.x * 256 + threadIdx.x;
    if (i >= N) return;
    float c     = fmaxf(cnt[i], 1.f);
    float avg   = numer[i] / c;
    float score = -(density[i] / (avg + EPS));
    out[i] = score;
    bool flag = score < -0.5f;
    out[N + i] = flag ? 1.f : 0.f;
    const float* lg = logits + (size_t)i * NC;
    float best = lg[0]; int bi = 0;
    #pragma unroll
    for (int k = 1; k < NC; ++k) { float x = lg[k]; if (x > best) { best = x; bi = k; } }
    out[2 * N + i] = flag ? -1.f : (float)bi;
}

extern "C" void kernel_launch(void* const* d_in, const int* in_sizes, int n_in,
                              void* d_out, int out_size, void* d_ws, size_t ws_size,
                              hipStream_t stream) {
    const float* X      = (const float*)d_in[0];
    const float* logits = (const float*)d_in[1];
    float* out = (float*)d_out;

    char* w = (char*)d_ws;
    auto alloc = [&](size_t bytes) { char* p = w; w += (bytes + 255) & ~(size_t)255; return p; };
    float* sq      = (float*)alloc((size_t)N * 4);
    float* T       = (float*)alloc((size_t)N * 4);
    float* density = (float*)alloc((size_t)N * 4);
    float* numer   = (float*)alloc((size_t)N * 4);
    float* cntb    = (float*)alloc((size_t)N * 4);
    int*   flagv   = (int*)alloc((size_t)N * 4);
    int*   cnt8    = (int*)alloc((size_t)N * 4);
    int*   knn     = (int*)alloc((size_t)N * KNN * 4);
    float* xbsum   = (float*)alloc(512);
    float* wvsum   = (float*)alloc(512);
    float* scal    = (float*)alloc(256);
    float* M       = (float*)alloc(65536);
    float* Mpart   = (float*)alloc((size_t)128 * 16384 * 4);
    float* Y       = (float*)alloc((size_t)N * 128 * 4);
    unsigned long long* list = (unsigned long long*)alloc((size_t)N * CAP * 8);

    hipMemsetAsync(cnt8,  0, (size_t)N * 4, stream);
    hipMemsetAsync(numer, 0, (size_t)N * 4, stream);
    hipMemsetAsync(cntb,  0, (size_t)N * 4, stream);
    hipMemsetAsync(xbsum, 0, 512, stream);
    hipMemsetAsync(wvsum, 0, 512, stream);

    k_sqnorm  <<<N, 64, 0, stream>>>(X, sq);
    k_colstats<<<64, 256, 0, stream>>>(X, sq, xbsum, wvsum);
    k_sqred   <<<1, 256, 0, stream>>>(sq, scal);
    k_Mpart   <<<128, 256, 0, stream>>>(X, Mpart);
    k_Mred    <<<64, 256, 0, stream>>>(Mpart, M);
    k_gemmY   <<<dim3(2, 128), 256, 0, stream>>>(X, M, Y);
    k_thresh  <<<N / 4, 256, 0, stream>>>(X, Y, sq, xbsum, wvsum, scal, T);
    k_fused   <<<8256, 256, 0, stream>>>(X, sq, T, list, cnt8);
    k_top     <<<N, 64, 0, stream>>>(list, cnt8, knn, density, flagv);
    k_fb      <<<N, 256, 0, stream>>>(X, sq, flagv, knn, density);
    k_scatter <<<(N * KNN + 255) / 256, 256, 0, stream>>>(knn, density, numer, cntb);
    k_final   <<<(N + 255) / 256, 256, 0, stream>>>(density, numer, cntb, logits, out);
}

// Round 4
// 330.017 us; speedup vs baseline: 6.6012x; 6.6012x over previous
//
#include <hip/hip_runtime.h>
#include <cstdint>
#include <cstddef>

#define N 8192
#define D 128
#define KNN 20
#define NC 10
#define CAP 2048
constexpr float EPS = 1e-10f;

typedef __attribute__((ext_vector_type(8))) short short8;
typedef __attribute__((ext_vector_type(4))) float f32x4;

// bf16 round-to-nearest-even, pure bit ops (no hip_bf16 header)
__device__ inline unsigned short f32_to_bf16_rne(float x) {
    unsigned u = __float_as_uint(x);
    unsigned r = u + 0x7FFFu + ((u >> 16) & 1u);
    return (unsigned short)(r >> 16);
}
__device__ inline float bf16_to_f32(unsigned short h) {
    return __uint_as_float((unsigned)h << 16);
}

// ---------------- K1: squared norms (exact fp32) ----------------
__global__ void k_sqnorm(const float* __restrict__ X, float* __restrict__ sq) {
    int row = blockIdx.x;
    int lane = threadIdx.x;
    const float2* X2 = (const float2*)(X + (size_t)row * D);
    float2 a = X2[lane];
    float s = a.x * a.x + a.y * a.y;
    #pragma unroll
    for (int off = 32; off; off >>= 1) s += __shfl_down(s, off, 64);
    if (lane == 0) sq[row] = s;
}

// ---------------- K2: split X into bf16 hi + lo ----------------
__global__ void k_split(const float* __restrict__ X, unsigned short* __restrict__ Xhi,
                        unsigned short* __restrict__ Xlo) {
    int i = blockIdx.x * 256 + threadIdx.x;     // 1M elems / 4
    const float4* X4 = (const float4*)X;
    float4 x = X4[i];
    unsigned short h[4], l[4];
    float xs[4] = {x.x, x.y, x.z, x.w};
    #pragma unroll
    for (int q = 0; q < 4; ++q) {
        h[q] = f32_to_bf16_rne(xs[q]);
        float hf = bf16_to_f32(h[q]);
        l[q] = f32_to_bf16_rne(xs[q] - hf);
    }
    *(ushort4*)&Xhi[(size_t)i * 4] = make_ushort4(h[0], h[1], h[2], h[3]);
    *(ushort4*)&Xlo[(size_t)i * 4] = make_ushort4(l[0], l[1], l[2], l[3]);
}

// ---------------- K3: MFMA split-bf16 distance tile (256 rows x 128 cols / block) ----
// d2 = sq_i + sq_j - 2*(hi.hi + hi.lo + lo.hi); banded output.
#define ASTRIDE 40   // bf16 elems per LDS row (32 data + 8 pad); 80 B, 16B-aligned
__global__ __launch_bounds__(256) void k_distm(
        const unsigned short* __restrict__ Xhi, const unsigned short* __restrict__ Xlo,
        const float* __restrict__ sqn, float* __restrict__ d2, int R0) {
    __shared__ unsigned short sAhi[256 * ASTRIDE];
    __shared__ unsigned short sAlo[256 * ASTRIDE];
    __shared__ unsigned short sBhi[128 * ASTRIDE];
    __shared__ unsigned short sBlo[128 * ASTRIDE];

    const int t    = threadIdx.x;
    const int lane = t & 63;
    const int w    = t >> 6;
    const int wr   = w >> 1;          // 0..1 : 128-row half
    const int wc   = w & 1;           // 0..1 : 64-col half
    const int lrow = lane & 15;       // fragment row within 16
    const int lkg  = lane >> 4;       // 0..3 : k-group (8 bf16 each)

    const int rowTile = R0 + blockIdx.y * 256;
    const int colTile = blockIdx.x * 128;

    f32x4 acc[8][4];
    #pragma unroll
    for (int i = 0; i < 8; ++i)
        #pragma unroll
        for (int j = 0; j < 4; ++j) acc[i][j] = (f32x4){0.f, 0.f, 0.f, 0.f};

    for (int kc = 0; kc < 4; ++kc) {            // four K-chunks of 32
        const int kb = kc * 32;
        __syncthreads();
        // stage A (256 rows): 1024 16B-chunks / 256 thr = 4 each
        #pragma unroll
        for (int p = 0; p < 4; ++p) {
            int u = t + 256 * p, r = u >> 2, c = u & 3;
            size_t g = (size_t)(rowTile + r) * 128 + kb + c * 8;
            *(uint4*)&sAhi[r * ASTRIDE + c * 8] = *(const uint4*)&Xhi[g];
            *(uint4*)&sAlo[r * ASTRIDE + c * 8] = *(const uint4*)&Xlo[g];
        }
        // stage B (128 rows): 512 chunks / 256 thr = 2 each
        #pragma unroll
        for (int p = 0; p < 2; ++p) {
            int u = t + 256 * p, r = u >> 2, c = u & 3;
            size_t g = (size_t)(colTile + r) * 128 + kb + c * 8;
            *(uint4*)&sBhi[r * ASTRIDE + c * 8] = *(const uint4*)&Xhi[g];
            *(uint4*)&sBlo[r * ASTRIDE + c * 8] = *(const uint4*)&Xlo[g];
        }
        __syncthreads();

        short8 a[8], b[4];
        // pass 1: hi . hi
        #pragma unroll
        for (int i = 0; i < 8; ++i)
            a[i] = *(const short8*)&sAhi[(wr * 128 + 16 * i + lrow) * ASTRIDE + lkg * 8];
        #pragma unroll
        for (int j = 0; j < 4; ++j)
            b[j] = *(const short8*)&sBhi[(wc * 64 + 16 * j + lrow) * ASTRIDE + lkg * 8];
        #pragma unroll
        for (int i = 0; i < 8; ++i)
            #pragma unroll
            for (int j = 0; j < 4; ++j)
                acc[i][j] = __builtin_amdgcn_mfma_f32_16x16x32_bf16(a[i], b[j], acc[i][j], 0, 0, 0);
        // pass 2: hi . lo   (reload b only)
        #pragma unroll
        for (int j = 0; j < 4; ++j)
            b[j] = *(const short8*)&sBlo[(wc * 64 + 16 * j + lrow) * ASTRIDE + lkg * 8];
        #pragma unroll
        for (int i = 0; i < 8; ++i)
            #pragma unroll
            for (int j = 0; j < 4; ++j)
                acc[i][j] = __builtin_amdgcn_mfma_f32_16x16x32_bf16(a[i], b[j], acc[i][j], 0, 0, 0);
        // pass 3: lo . hi   (reload both)
        #pragma unroll
        for (int i = 0; i < 8; ++i)
            a[i] = *(const short8*)&sAlo[(wr * 128 + 16 * i + lrow) * ASTRIDE + lkg * 8];
        #pragma unroll
        for (int j = 0; j < 4; ++j)
            b[j] = *(const short8*)&sBhi[(wc * 64 + 16 * j + lrow) * ASTRIDE + lkg * 8];
        #pragma unroll
        for (int i = 0; i < 8; ++i)
            #pragma unroll
            for (int j = 0; j < 4; ++j)
                acc[i][j] = __builtin_amdgcn_mfma_f32_16x16x32_bf16(a[i], b[j], acc[i][j], 0, 0, 0);
    }

    // epilogue: C/D layout col=lane&15, row=(lane>>4)*4+reg  [m89/m91]
    float sqb[4];
    #pragma unroll
    for (int j = 0; j < 4; ++j)
        sqb[j] = sqn[colTile + wc * 64 + 16 * j + lrow];
    #pragma unroll
    for (int i = 0; i < 8; ++i) {
        int lr0 = blockIdx.y * 256 + wr * 128 + 16 * i + lkg * 4;   // band-local row (reg 0)
        #pragma unroll
        for (int q = 0; q < 4; ++q) {
            float sa = sqn[R0 + lr0 + q];
            #pragma unroll
            for (int j = 0; j < 4; ++j) {
                float d = fmaxf(fmaf(-2.f, acc[i][j][q], sa + sqb[j]), 0.f);
                d2[(size_t)(lr0 + q) * N + colTile + wc * 64 + 16 * j + lrow] = d;
            }
        }
    }
}

// ---------------- K4: exact 20-NN per row (threshold filter + u64 min rounds) ----
__global__ __launch_bounds__(256) void k_select(const float* __restrict__ d2, int R0,
                                                int* __restrict__ knn_idx,
                                                float* __restrict__ density) {
    __shared__ float redf1[256], redf2[256];
    __shared__ int   redi[256];
    __shared__ unsigned long long list[CAP];
    __shared__ int lc;

    int lrow = blockIdx.x;
    int row  = R0 + lrow;
    int t    = threadIdx.x;
    const float4* rp = (const float4*)(d2 + (size_t)lrow * N);

    float v[32];
    #pragma unroll
    for (int p = 0; p < 8; ++p) {
        float4 g = rp[t + 256 * p];
        v[4 * p + 0] = g.x; v[4 * p + 1] = g.y; v[4 * p + 2] = g.z; v[4 * p + 3] = g.w;
    }

    float s1 = 0.f, s2 = 0.f;
    #pragma unroll
    for (int i = 0; i < 32; ++i) { s1 += v[i]; s2 = fmaf(v[i], v[i], s2); }
    redf1[t] = s1; redf2[t] = s2; __syncthreads();
    for (int sft = 128; sft; sft >>= 1) {
        if (t < sft) { redf1[t] += redf1[t + sft]; redf2[t] += redf2[t + sft]; }
        __syncthreads();
    }
    float mu    = redf1[0] * (1.f / N);
    float var   = redf2[0] * (1.f / N) - mu * mu;
    float sigma = sqrtf(fmaxf(var, 0.f)) + 1e-6f;
    __syncthreads();

    // first probe z=2.6 (expected ~40 survivors); tiered acceptance window
    float Tlo = 0.f, Thi = mu, T = mu - 2.6f * sigma;
    if (T <= 0.f) T = 0.5f * (Tlo + Thi);
    for (int it = 0; it < 32; ++it) {
        int c = 0;
        #pragma unroll
        for (int i = 0; i < 32; ++i) c += (v[i] < T) ? 1 : 0;
        redi[t] = c; __syncthreads();
        for (int sft = 128; sft; sft >>= 1) {
            if (t < sft) redi[t] += redi[t + sft];
            __syncthreads();
        }
        int n = redi[0]; __syncthreads();
        int lim = it < 4 ? 512 : (it < 8 ? 1024 : CAP);
        if (n >= KNN && n <= lim) break;
        if (n < KNN) Tlo = T; else Thi = T;
        T = 0.5f * (Tlo + Thi);
    }

    if (t == 0) lc = 0;
    __syncthreads();
    #pragma unroll
    for (int i = 0; i < 32; ++i) {
        if (v[i] < T) {
            int pos = atomicAdd(&lc, 1);
            if (pos < CAP) {
                int j = 4 * (t + 256 * (i >> 2)) + (i & 3);
                unsigned long long key =
                    ((unsigned long long)__float_as_uint(v[i]) << 14) |
                    (unsigned long long)(j + 1);
                list[pos] = key;
            }
        }
    }
    __syncthreads();
    int n = min(lc, CAP);

    if (t < 64) {
        unsigned long long last = 0ull;
        float sumd = 0.f;
        for (int r = 0; r < KNN; ++r) {
            unsigned long long m = ~0ull;
            for (int sIdx = t; sIdx < n; sIdx += 64) {
                unsigned long long k = list[sIdx];
                if (k > last && k < m) m = k;
            }
            #pragma unroll
            for (int off = 32; off; off >>= 1) {
                unsigned long long o = __shfl_down(m, off, 64);
                if (o < m) m = o;
            }
            m = __shfl(m, 0, 64);
            last = m;
            if (t == 0) {
                int j = (int)(m & 16383ull) - 1;
                if (j < 0) j = 0; if (j >= N) j = N - 1;
                knn_idx[(size_t)row * KNN + r] = j;
                float dv = __uint_as_float((unsigned)(m >> 14));
                sumd += sqrtf(dv);
            }
        }
        if (t == 0) density[row] = 1.f / (sumd * (1.f / KNN) + EPS);
    }
}

// ---------------- K5: scatter knn + rnn (deduped) contributions ----------------
__global__ void k_scatter(const int* __restrict__ knn_idx, const float* __restrict__ density,
                          float* __restrict__ numer, float* __restrict__ cnt) {
    int p = blockIdx.x * 256 + threadIdx.x;
    if (p >= N * KNN) return;
    int i = p / KNN;
    int j = knn_idx[p];
    atomicAdd(&numer[i], density[j]);
    atomicAdd(&cnt[i], 1.f);
    bool found = false;
    const int* kj = knn_idx + (size_t)j * KNN;
    #pragma unroll
    for (int m = 0; m < KNN; ++m) found |= (kj[m] == i);
    if (!found) {
        atomicAdd(&numer[j], density[i]);
        atomicAdd(&cnt[j], 1.f);
    }
}

// ---------------- K6: scores, flags, class preds ----------------
__global__ void k_final(const float* __restrict__ density, const float* __restrict__ numer,
                        const float* __restrict__ cnt, const float* __restrict__ logits,
                        float* __restrict__ out) {
    int i = blockIdx.x * 256 + threadIdx.x;
    if (i >= N) return;
    float c     = fmaxf(cnt[i], 1.f);
    float avg   = numer[i] / c;
    float score = -(density[i] / (avg + EPS));
    out[i] = score;
    bool flag = score < -0.5f;
    out[N + i] = flag ? 1.f : 0.f;
    const float* lg = logits + (size_t)i * NC;
    float best = lg[0]; int bi = 0;
    #pragma unroll
    for (int k = 1; k < NC; ++k) { float x = lg[k]; if (x > best) { best = x; bi = k; } }
    out[2 * N + i] = flag ? -1.f : (float)bi;
}

extern "C" void kernel_launch(void* const* d_in, const int* in_sizes, int n_in,
                              void* d_out, int out_size, void* d_ws, size_t ws_size,
                              hipStream_t stream) {
    const float* X      = (const float*)d_in[0];
    const float* logits = (const float*)d_in[1];
    float* out = (float*)d_out;

    char* w = (char*)d_ws;
    auto alloc = [&](size_t bytes) { char* p = w; w += (bytes + 255) & ~(size_t)255; return p; };
    float* sq      = (float*)alloc((size_t)N * 4);
    float* density = (float*)alloc((size_t)N * 4);
    float* numer   = (float*)alloc((size_t)N * 4);
    float* cntb    = (float*)alloc((size_t)N * 4);
    int*   knn     = (int*)alloc((size_t)N * KNN * 4);
    unsigned short* Xhi = (unsigned short*)alloc((size_t)N * D * 2);
    unsigned short* Xlo = (unsigned short*)alloc((size_t)N * D * 2);
    float* d2band  = (float*)w;
    size_t used  = (size_t)(w - (char*)d_ws);
    size_t avail = ws_size > used ? ws_size - used : 0;
    int band = (int)(avail / ((size_t)N * 4));
    band = (band / 256) * 256;
    if (band > N) band = N;
    if (band < 256) band = 256;                 // requires ws >= ~13 MB (R2 showed >=147 MB)

    hipMemsetAsync(numer, 0, (size_t)N * 4, stream);
    hipMemsetAsync(cntb,  0, (size_t)N * 4, stream);

    k_sqnorm<<<N, 64, 0, stream>>>(X, sq);
    k_split <<<(N * D / 4 + 255) / 256, 256, 0, stream>>>(X, Xhi, Xlo);

    for (int R0 = 0; R0 < N; R0 += band) {
        int rows = min(band, N - R0);
        dim3 g(N / 128, rows / 256);
        k_distm <<<g, 256, 0, stream>>>(Xhi, Xlo, sq, d2band, R0);
        k_select<<<rows, 256, 0, stream>>>(d2band, R0, knn, density);
    }

    k_scatter<<<(N * KNN + 255) / 256, 256, 0, stream>>>(knn, density, numer, cntb);
    k_final  <<<(N + 255) / 256, 256, 0, stream>>>(density, numer, cntb, logits, out);
}